// Round 6
// baseline (138.655 us; speedup 1.0000x reference)
//
#include <hip/hip_runtime.h>
#include <math.h>

#define NB    512
#define NP    4096
#define BLOCK 256
#define KPT   2
#define CHUNK (BLOCK * KPT)     // 512 points per block
#define NCHUNK (NP / CHUNK)     // 8 chunks per batch element

typedef float v2f __attribute__((ext_vector_type(2)));

// fp32 sin, correctly rounded, for BOTH lanes of a v2f.
// Same arithmetic as R5's sin_cr (fp64 Taylor after exact revolution
// reduction), two independent chains for ILP. noinline: one shared,
// I$-resident body instead of 61 inlined ~45-instruction copies.
__device__ __attribute__((noinline)) v2f sin2_cr(v2f tf) {
#pragma clang fp contract(off)
    double t0 = (double)tf.x;
    double t1 = (double)tf.y;
    double y0 = t0 * 0.15915494309189535;    // t/(2pi)
    double y1 = t1 * 0.15915494309189535;
    double f0 = y0 - rint(y0);               // [-0.5,0.5], exact subtraction
    double f1 = y1 - rint(y1);
    double x0 = f0 * 6.283185307179586;      // [-pi,pi]
    double x1 = f1 * 6.283185307179586;
    double x20 = x0 * x0;
    double x21 = x1 * x1;
    double p0, p1;
    p0 =                   1.0 / 51090942171709440000.0;   // +1/21!
    p1 =                   1.0 / 51090942171709440000.0;
    p0 = fma(p0, x20, -1.0 / 121645100408832000.0);        // -1/19!
    p1 = fma(p1, x21, -1.0 / 121645100408832000.0);
    p0 = fma(p0, x20,  1.0 / 355687428096000.0);           // +1/17!
    p1 = fma(p1, x21,  1.0 / 355687428096000.0);
    p0 = fma(p0, x20, -1.0 / 1307674368000.0);             // -1/15!
    p1 = fma(p1, x21, -1.0 / 1307674368000.0);
    p0 = fma(p0, x20,  1.0 / 6227020800.0);                // +1/13!
    p1 = fma(p1, x21,  1.0 / 6227020800.0);
    p0 = fma(p0, x20, -1.0 / 39916800.0);                  // -1/11!
    p1 = fma(p1, x21, -1.0 / 39916800.0);
    p0 = fma(p0, x20,  1.0 / 362880.0);                    // +1/9!
    p1 = fma(p1, x21,  1.0 / 362880.0);
    p0 = fma(p0, x20, -1.0 / 5040.0);                      // -1/7!
    p1 = fma(p1, x21, -1.0 / 5040.0);
    p0 = fma(p0, x20,  1.0 / 120.0);                       // +1/5!
    p1 = fma(p1, x21,  1.0 / 120.0);
    p0 = fma(p0, x20, -1.0 / 6.0);                         // -1/3!
    p1 = fma(p1, x21, -1.0 / 6.0);
    double x30 = x20 * x0;
    double x31 = x21 * x1;
    v2f r;
    r.x = (float)fma(p0, x30, x0);
    r.y = (float)fma(p1, x31, x1);
    return r;
}

// numpy n=20 dot (SSE2 npyv, no FMA): 4 columns, chained mul+add per column,
// tree (c0+c2)+(c1+c3). Evaluated for 2 points at once (per-lane identical).
__device__ __forceinline__ v2f dot20_np2(const float* __restrict__ wr,
                                         const v2f* __restrict__ h) {
#pragma clang fp contract(off)
    v2f c0 = h[0] * wr[0];
    v2f c1 = h[1] * wr[1];
    v2f c2 = h[2] * wr[2];
    v2f c3 = h[3] * wr[3];
    c0 = c0 + h[4]  * wr[4];   c1 = c1 + h[5]  * wr[5];
    c2 = c2 + h[6]  * wr[6];   c3 = c3 + h[7]  * wr[7];
    c0 = c0 + h[8]  * wr[8];   c1 = c1 + h[9]  * wr[9];
    c2 = c2 + h[10] * wr[10];  c3 = c3 + h[11] * wr[11];
    c0 = c0 + h[12] * wr[12];  c1 = c1 + h[13] * wr[13];
    c2 = c2 + h[14] * wr[14];  c3 = c3 + h[15] * wr[15];
    c0 = c0 + h[16] * wr[16];  c1 = c1 + h[17] * wr[17];
    c2 = c2 + h[18] * wr[18];  c3 = c3 + h[19] * wr[19];
    v2f s02 = c0 + c2;
    v2f s13 = c1 + c3;
    return s02 + s13;
}

// Param layout per batch (921 floats):
// [0,40) W1(20x2)  [40,60) b1 | [60,460) W2(20x20) [460,480) b2
// [480,880) W3(20x20) [880,900) b3 | [900,920) W4(1x20) [920] b4
// Weights are wave-uniform (per-block batch) -> scalar (SMEM) loads, no LDS.
__global__ __launch_bounds__(BLOCK) void siren20_np3_kernel(
    const float* __restrict__ coords,
    const float* __restrict__ wflat,
    float* __restrict__ out)
{
#pragma clang fp contract(off)
    const int b   = blockIdx.y;
    const int tid = threadIdx.x;
    const float* __restrict__ w = wflat + (size_t)b * 921;

    const int p0 = blockIdx.x * CHUNK + tid;   // two coalesced points
    const int p1 = p0 + BLOCK;
    const float2* cbase = (const float2*)(coords + (size_t)b * NP * 2);
    const float2 ca = cbase[p0];
    const float2 cc = cbase[p1];
    v2f cx; cx.x = ca.x; cx.y = cc.x;
    v2f cy; cy.x = ca.y; cy.y = cc.y;

    v2f h[20], g[20];

    // Layer 1: n=2 scalar dot, mul+add (no fma), then +b, *20, sin.
    #pragma unroll
    for (int j = 0; j < 20; ++j) {
        v2f s = cx * w[2 * j];
        s = s + cy * w[2 * j + 1];
        v2f u = s + w[40 + j];
        v2f t = u * 20.0f;
        h[j] = sin2_cr(t);
    }

    // Layer 2: W at 60, b at 460
    #pragma unroll
    for (int j = 0; j < 20; ++j) {
        v2f a = dot20_np2(&w[60 + 20 * j], h);
        v2f u = a + w[460 + j];
        v2f t = u * 20.0f;
        g[j] = sin2_cr(t);
    }

    // Layer 3: W at 480, b at 880
    #pragma unroll
    for (int j = 0; j < 20; ++j) {
        v2f a = dot20_np2(&w[480 + 20 * j], g);
        v2f u = a + w[880 + j];
        v2f t = u * 20.0f;
        h[j] = sin2_cr(t);
    }

    // Layer 4: W at 900, b at 920, clip
    v2f a = dot20_np2(&w[900], h);
    v2f u = a + w[920];
    float r0 = fminf(fmaxf(u.x, 0.0f), 1.0f);
    float r1 = fminf(fmaxf(u.y, 0.0f), 1.0f);

    float* ob = out + (size_t)b * NP;
    ob[p0] = r0;
    ob[p1] = r1;
}

extern "C" void kernel_launch(void* const* d_in, const int* in_sizes, int n_in,
                              void* d_out, int out_size, void* d_ws, size_t ws_size,
                              hipStream_t stream) {
    const float* coords = (const float*)d_in[0];
    const float* wflat  = (const float*)d_in[1];
    float* out = (float*)d_out;
    dim3 grid(NCHUNK, NB);
    siren20_np3_kernel<<<grid, dim3(BLOCK), 0, stream>>>(coords, wflat, out);
}

// Round 7
// 133.607 us; speedup vs baseline: 1.0378x; 1.0378x over previous
//
#include <hip/hip_runtime.h>
#include <math.h>

#define NB    512
#define NP    4096
#define BLOCK 256
#define KPT   2
#define CHUNK (BLOCK * KPT)     // 512 points per block
#define NCHUNK (NP / CHUNK)     // 8 chunks per batch element

typedef float v2f __attribute__((ext_vector_type(2)));

// fp32 sin, correctly rounded (fp64 Taylor after exact revolution reduction).
// Bit-identical to R4/R5/R6 sin. Inlined (R6 showed noinline call ABI costs
// more than it saves).
__device__ __forceinline__ float sin_cr(float tf) {
#pragma clang fp contract(off)
    double t  = (double)tf;
    double y  = t * 0.15915494309189535;    // t/(2pi)
    double f  = y - rint(y);                // [-0.5,0.5], exact subtraction
    double x  = f * 6.283185307179586;      // [-pi,pi]
    double x2 = x * x;
    double p;
    p =                  1.0 / 51090942171709440000.0;   // +1/21!
    p = fma(p, x2, -1.0 / 121645100408832000.0);         // -1/19!
    p = fma(p, x2,  1.0 / 355687428096000.0);            // +1/17!
    p = fma(p, x2, -1.0 / 1307674368000.0);              // -1/15!
    p = fma(p, x2,  1.0 / 6227020800.0);                 // +1/13!
    p = fma(p, x2, -1.0 / 39916800.0);                   // -1/11!
    p = fma(p, x2,  1.0 / 362880.0);                     // +1/9!
    p = fma(p, x2, -1.0 / 5040.0);                       // -1/7!
    p = fma(p, x2,  1.0 / 120.0);                        // +1/5!
    p = fma(p, x2, -1.0 / 6.0);                          // -1/3!
    double x3 = x2 * x;
    return (float)fma(p, x3, x);
}

// numpy n=20 dot (SSE2 npyv, no FMA): 4 columns, chained mul+add per column,
// tree (c0+c2)+(c1+c3). Two points at once (per-lane identical semantics).
__device__ __forceinline__ v2f dot20_np2(const float* __restrict__ wr,
                                         const v2f* __restrict__ h) {
#pragma clang fp contract(off)
    v2f c0 = h[0] * wr[0];
    v2f c1 = h[1] * wr[1];
    v2f c2 = h[2] * wr[2];
    v2f c3 = h[3] * wr[3];
    c0 = c0 + h[4]  * wr[4];   c1 = c1 + h[5]  * wr[5];
    c2 = c2 + h[6]  * wr[6];   c3 = c3 + h[7]  * wr[7];
    c0 = c0 + h[8]  * wr[8];   c1 = c1 + h[9]  * wr[9];
    c2 = c2 + h[10] * wr[10];  c3 = c3 + h[11] * wr[11];
    c0 = c0 + h[12] * wr[12];  c1 = c1 + h[13] * wr[13];
    c2 = c2 + h[14] * wr[14];  c3 = c3 + h[15] * wr[15];
    c0 = c0 + h[16] * wr[16];  c1 = c1 + h[17] * wr[17];
    c2 = c2 + h[18] * wr[18];  c3 = c3 + h[19] * wr[19];
    v2f s02 = c0 + c2;
    v2f s13 = c1 + c3;
    return s02 + s13;
}

// Param layout per batch (921 floats):
// [0,40) W1(20x2)  [40,60) b1 | [60,460) W2(20x20) [460,480) b2
// [480,880) W3(20x20) [880,900) b3 | [900,920) W4(1x20) [920] b4
// Weights staged in LDS; all lanes read the same address -> broadcast,
// conflict-free, and adjacent elements merge into ds_read_b128.
__global__ __launch_bounds__(BLOCK) void siren20_np4_kernel(
    const float* __restrict__ coords,
    const float* __restrict__ wflat,
    float* __restrict__ out)
{
#pragma clang fp contract(off)
    __shared__ __align__(16) float w[928];
    const int b   = blockIdx.y;
    const int tid = threadIdx.x;
    const float* __restrict__ wg = wflat + (size_t)b * 921;

    #pragma unroll
    for (int k = 0; k < 4; ++k) {
        int i = tid + k * BLOCK;
        if (i < 921) w[i] = wg[i];
    }
    __syncthreads();

    const int p0 = blockIdx.x * CHUNK + tid;   // two coalesced points
    const int p1 = p0 + BLOCK;
    const float2* cbase = (const float2*)(coords + (size_t)b * NP * 2);
    const float2 ca = cbase[p0];
    const float2 cc = cbase[p1];
    v2f cx; cx.x = ca.x; cx.y = cc.x;
    v2f cy; cy.x = ca.y; cy.y = cc.y;

    v2f h[20], g[20];

    // Layer 1: n=2 scalar dot, mul+add (no fma), then +b, *20, sin.
    #pragma unroll
    for (int j = 0; j < 20; ++j) {
        v2f s = cx * w[2 * j];
        s = s + cy * w[2 * j + 1];
        v2f u = s + w[40 + j];
        v2f t = u * 20.0f;
        h[j].x = sin_cr(t.x);
        h[j].y = sin_cr(t.y);
    }

    // Layer 2: W at 60, b at 460
    #pragma unroll
    for (int j = 0; j < 20; ++j) {
        v2f a = dot20_np2(&w[60 + 20 * j], h);
        v2f u = a + w[460 + j];
        v2f t = u * 20.0f;
        g[j].x = sin_cr(t.x);
        g[j].y = sin_cr(t.y);
    }

    // Layer 3: W at 480, b at 880
    #pragma unroll
    for (int j = 0; j < 20; ++j) {
        v2f a = dot20_np2(&w[480 + 20 * j], g);
        v2f u = a + w[880 + j];
        v2f t = u * 20.0f;
        h[j].x = sin_cr(t.x);
        h[j].y = sin_cr(t.y);
    }

    // Layer 4: W at 900, b at 920, clip
    v2f a = dot20_np2(&w[900], h);
    v2f u = a + w[920];
    float r0 = fminf(fmaxf(u.x, 0.0f), 1.0f);
    float r1 = fminf(fmaxf(u.y, 0.0f), 1.0f);

    float* ob = out + (size_t)b * NP;
    ob[p0] = r0;
    ob[p1] = r1;
}

extern "C" void kernel_launch(void* const* d_in, const int* in_sizes, int n_in,
                              void* d_out, int out_size, void* d_ws, size_t ws_size,
                              hipStream_t stream) {
    const float* coords = (const float*)d_in[0];
    const float* wflat  = (const float*)d_in[1];
    float* out = (float*)d_out;
    dim3 grid(NCHUNK, NB);
    siren20_np4_kernel<<<grid, dim3(BLOCK), 0, stream>>>(coords, wflat, out);
}

// Round 8
// 112.346 us; speedup vs baseline: 1.2342x; 1.1892x over previous
//
#include <hip/hip_runtime.h>
#include <math.h>

#define NB    512
#define NP    4096
#define BLOCK 256
#define KPT   2
#define CHUNK (BLOCK * KPT)     // 512 points per block
#define NCHUNK (NP / CHUNK)     // 8 chunks per batch element

typedef float v2f __attribute__((ext_vector_type(2)));

// fp32 sin, correctly rounded (fp64 Taylor after exact revolution reduction).
// Bit-identical to R4..R7. Used ONLY for layer 1, where error amplification
// to the output is ~1e5x.
__device__ __forceinline__ float sin_cr(float tf) {
#pragma clang fp contract(off)
    double t  = (double)tf;
    double y  = t * 0.15915494309189535;    // t/(2pi)
    double f  = y - rint(y);                // [-0.5,0.5], exact subtraction
    double x  = f * 6.283185307179586;      // [-pi,pi]
    double x2 = x * x;
    double p;
    p =                  1.0 / 51090942171709440000.0;   // +1/21!
    p = fma(p, x2, -1.0 / 121645100408832000.0);         // -1/19!
    p = fma(p, x2,  1.0 / 355687428096000.0);            // +1/17!
    p = fma(p, x2, -1.0 / 1307674368000.0);              // -1/15!
    p = fma(p, x2,  1.0 / 6227020800.0);                 // +1/13!
    p = fma(p, x2, -1.0 / 39916800.0);                   // -1/11!
    p = fma(p, x2,  1.0 / 362880.0);                     // +1/9!
    p = fma(p, x2, -1.0 / 5040.0);                       // -1/7!
    p = fma(p, x2,  1.0 / 120.0);                        // +1/5!
    p = fma(p, x2, -1.0 / 6.0);                          // -1/3!
    double x3 = x2 * x;
    return (float)fma(p, x3, x);
}

// Fast all-f32 sin for layers 2/3 (error amplification there is 63x / 4000x
// smaller than L1). |t| <= ~800. Reduction: n = rint(t/2pi), 2-part
// Cody-Waite 2pi (6.28125 exact * n for n<2^16; residual c2 to 1e-10).
// Taylor odd poly to x^19 on [-pi,pi]; total |err vs true sin| <= ~5e-7.
// contract(fast) so mul+add fuse into v_pk_fma_f32 (both points packed).
__device__ __forceinline__ v2f sin2_fast(v2f t) {
#pragma clang fp contract(fast)
    v2f y = t * 0.15915494309189535f;
    v2f n;
    n.x = rintf(y.x);
    n.y = rintf(y.y);
    v2f r = t - n * 6.28125f;            // exact product, fused -> fma
    r = r - n * 1.93530717e-3f;          // fused -> fma
    v2f r2 = r * r;
    v2f p;
    p.x = -8.22063525e-18f; p.y = -8.22063525e-18f;      // -1/19!
    p = p * r2 + 2.81145725e-15f;                        // +1/17!
    p = p * r2 + -7.64716373e-13f;                       // -1/15!
    p = p * r2 + 1.60590438e-10f;                        // +1/13!
    p = p * r2 + -2.50521084e-8f;                        // -1/11!
    p = p * r2 + 2.75573192e-6f;                         // +1/9!
    p = p * r2 + -1.98412698e-4f;                        // -1/7!
    p = p * r2 + 8.33333333e-3f;                         // +1/5!
    p = p * r2 + -1.66666667e-1f;                        // -1/3!
    v2f r3 = r2 * r;
    return p * r3 + r;                                   // fused -> fma
}

// numpy n=20 dot (SSE2 npyv, no FMA): 4 columns, chained mul+add per column,
// tree (c0+c2)+(c1+c3). Two points at once (per-lane identical semantics).
__device__ __forceinline__ v2f dot20_np2(const float* __restrict__ wr,
                                         const v2f* __restrict__ h) {
#pragma clang fp contract(off)
    v2f c0 = h[0] * wr[0];
    v2f c1 = h[1] * wr[1];
    v2f c2 = h[2] * wr[2];
    v2f c3 = h[3] * wr[3];
    c0 = c0 + h[4]  * wr[4];   c1 = c1 + h[5]  * wr[5];
    c2 = c2 + h[6]  * wr[6];   c3 = c3 + h[7]  * wr[7];
    c0 = c0 + h[8]  * wr[8];   c1 = c1 + h[9]  * wr[9];
    c2 = c2 + h[10] * wr[10];  c3 = c3 + h[11] * wr[11];
    c0 = c0 + h[12] * wr[12];  c1 = c1 + h[13] * wr[13];
    c2 = c2 + h[14] * wr[14];  c3 = c3 + h[15] * wr[15];
    c0 = c0 + h[16] * wr[16];  c1 = c1 + h[17] * wr[17];
    c2 = c2 + h[18] * wr[18];  c3 = c3 + h[19] * wr[19];
    v2f s02 = c0 + c2;
    v2f s13 = c1 + c3;
    return s02 + s13;
}

// Param layout per batch (921 floats):
// [0,40) W1(20x2)  [40,60) b1 | [60,460) W2(20x20) [460,480) b2
// [480,880) W3(20x20) [880,900) b3 | [900,920) W4(1x20) [920] b4
__global__ __launch_bounds__(BLOCK) void siren20_np5_kernel(
    const float* __restrict__ coords,
    const float* __restrict__ wflat,
    float* __restrict__ out)
{
#pragma clang fp contract(off)
    __shared__ __align__(16) float w[928];
    const int b   = blockIdx.y;
    const int tid = threadIdx.x;
    const float* __restrict__ wg = wflat + (size_t)b * 921;

    #pragma unroll
    for (int k = 0; k < 4; ++k) {
        int i = tid + k * BLOCK;
        if (i < 921) w[i] = wg[i];
    }
    __syncthreads();

    const int p0 = blockIdx.x * CHUNK + tid;   // two coalesced points
    const int p1 = p0 + BLOCK;
    const float2* cbase = (const float2*)(coords + (size_t)b * NP * 2);
    const float2 ca = cbase[p0];
    const float2 cc = cbase[p1];
    v2f cx; cx.x = ca.x; cx.y = cc.x;
    v2f cy; cy.x = ca.y; cy.y = cc.y;

    v2f h[20], g[20];

    // Layer 1: n=2 scalar dot, mul+add (no fma), then +b, *20, CR sin.
    #pragma unroll
    for (int j = 0; j < 20; ++j) {
        v2f s = cx * w[2 * j];
        s = s + cy * w[2 * j + 1];
        v2f u = s + w[40 + j];
        v2f t = u * 20.0f;
        h[j].x = sin_cr(t.x);
        h[j].y = sin_cr(t.y);
    }

    // Layer 2: W at 60, b at 460 — fast f32 sin (amplification ~63x lower)
    #pragma unroll
    for (int j = 0; j < 20; ++j) {
        v2f a = dot20_np2(&w[60 + 20 * j], h);
        v2f u = a + w[460 + j];
        v2f t = u * 20.0f;
        g[j] = sin2_fast(t);
    }

    // Layer 3: W at 480, b at 880 — fast f32 sin
    #pragma unroll
    for (int j = 0; j < 20; ++j) {
        v2f a = dot20_np2(&w[480 + 20 * j], g);
        v2f u = a + w[880 + j];
        v2f t = u * 20.0f;
        h[j] = sin2_fast(t);
    }

    // Layer 4: W at 900, b at 920, clip
    v2f a = dot20_np2(&w[900], h);
    v2f u = a + w[920];
    float r0 = fminf(fmaxf(u.x, 0.0f), 1.0f);
    float r1 = fminf(fmaxf(u.y, 0.0f), 1.0f);

    float* ob = out + (size_t)b * NP;
    ob[p0] = r0;
    ob[p1] = r1;
}

extern "C" void kernel_launch(void* const* d_in, const int* in_sizes, int n_in,
                              void* d_out, int out_size, void* d_ws, size_t ws_size,
                              hipStream_t stream) {
    const float* coords = (const float*)d_in[0];
    const float* wflat  = (const float*)d_in[1];
    float* out = (float*)d_out;
    dim3 grid(NCHUNK, NB);
    siren20_np5_kernel<<<grid, dim3(BLOCK), 0, stream>>>(coords, wflat, out);
}